// Round 8
// baseline (209.945 us; speedup 1.0000x reference)
//
#include <hip/hip_runtime.h>

#define NN 50000
#define NE 800000
#define KD 256
#define CD 128
#define NB 196            // scan blocks: 196*256 = 50176 >= NN
#define GEMM_BLOCKS 782   // (NN+63)/64
#define HIST4_BLOCKS 782  // 800000 / (256 thr * 4 edges) = 781.25
#define META_BLOCKS 782   // same 4-edge tiling

typedef __attribute__((ext_vector_type(8))) short short8;
typedef __attribute__((ext_vector_type(4))) float floatx4;
typedef __attribute__((ext_vector_type(2))) float floatx2;

__device__ inline unsigned short f2bf(float f) {
    unsigned u = __float_as_uint(f);
    unsigned r = (u + 0x7FFFu + ((u >> 16) & 1u)) >> 16;   // RNE
    return (unsigned short)r;
}
__device__ inline float bf2f_lo(unsigned u) { return __uint_as_float(u << 16); }
__device__ inline float bf2f_hi(unsigned u) { return __uint_as_float(u & 0xFFFF0000u); }

// ===== prep: zero u32 histogram shadows + scan state (blocks < NB),
// W transpose (last 32 blocks) =====
__global__ __launch_bounds__(256) void prep(const float* __restrict__ W,
                                            unsigned short* __restrict__ Wt,
                                            unsigned* __restrict__ packedAll,
                                            unsigned long long* __restrict__ state) {
    __shared__ unsigned short t[32][33];
    if (blockIdx.x < NB) {
        const int g = blockIdx.x * 256 + threadIdx.x;
        if (g < NN) {
#pragma unroll
            for (int c = 0; c < 4; c++) packedAll[(size_t)c * NN + g] = 0u;
        }
        if (blockIdx.x == 0) {
            for (int i = threadIdx.x; i < NB * 8; i += 256) state[i] = 0ull;
        }
        return;
    }
    const int b2 = blockIdx.x - NB;          // [0,32): 8 k-tiles x 4 n-tiles
    const int bk = (b2 & 7) * 32;
    const int bn = (b2 >> 3) * 32;
    const int tx = threadIdx.x & 31;
    const int ty = threadIdx.x >> 5;
#pragma unroll
    for (int i = 0; i < 32; i += 8)
        t[ty + i][tx] = f2bf(W[(size_t)(bk + ty + i) * CD + bn + tx]);
    __syncthreads();
#pragma unroll
    for (int i = 0; i < 32; i += 8)
        Wt[(size_t)(bn + ty + i) * KD + bk + tx] = t[tx][ty + i];
}

// ===== fused: no-LDS GEMM tiles (blocks < GEMM_BLOCKS) + 4-edge hist (rest)
// GEMM: each lane loads its MFMA fragments DIRECTLY in consume layout —
// A from x (L3-resident), B from Wt (L2-resident). No LDS, no barriers:
// the old structure exposed ~500ns load latency per K-iter behind two
// __syncthreads (MfmaUtil 2.6%, 1.5M bank conflicts). 72 independent
// loads/lane now pipeline freely; other waves fill the stalls.
// hist: packed {count:8 | sum(ew) Q6.18:24}, 4 shadow copies; 4 edges/thread
// pipelines 4 independent atomics. copy=(tid>>6)&3 == (e>>8)&3 exactly.
__global__ __launch_bounds__(256) void fused_gemm_hist(
        const float* __restrict__ x, const unsigned short* __restrict__ Wt,
        unsigned short* __restrict__ hb,
        const int* __restrict__ col, const float* __restrict__ ew,
        unsigned* __restrict__ packedAll, unsigned short* __restrict__ rank) {
    if (blockIdx.x >= GEMM_BLOCKS) {
        const int e0 = ((blockIdx.x - GEMM_BLOCKS) * 256 + threadIdx.x) * 4;
        if (e0 < NE) {     // NE%4==0 -> full int4 groups
            const int4 c4 = *(const int4*)(col + e0);
            const float4 w4 = *(const float4*)(ew + e0);
            unsigned* packed = packedAll + (size_t)((threadIdx.x >> 6) & 3) * NN;
            const unsigned o0 = atomicAdd(&packed[c4.x], (1u << 24) + (unsigned)(w4.x * 262144.0f));
            const unsigned o1 = atomicAdd(&packed[c4.y], (1u << 24) + (unsigned)(w4.y * 262144.0f));
            const unsigned o2 = atomicAdd(&packed[c4.z], (1u << 24) + (unsigned)(w4.z * 262144.0f));
            const unsigned o3 = atomicAdd(&packed[c4.w], (1u << 24) + (unsigned)(w4.w * 262144.0f));
            ushort4 r;
            r.x = (unsigned short)(o0 >> 24);
            r.y = (unsigned short)(o1 >> 24);
            r.z = (unsigned short)(o2 >> 24);
            r.w = (unsigned short)(o3 >> 24);
            *(ushort4*)(rank + e0) = r;
        }
        return;
    }

    // ---------------- GEMM role: h = bf16(x) @ Wt^T, 64 rows x 128 ch / block
    const int tid  = threadIdx.x;
    const int wave = tid >> 6;
    const int lane = tid & 63;
    const int row0 = blockIdx.x * 64;
    const int m0   = wave * 16;
    const int lr   = lane & 15;
    const int quad = lane >> 4;

    const int grow_a = row0 + m0 + lr;           // A row this lane consumes
    const bool ok = grow_a < NN;
    const float* xp = x + (size_t)grow_a * KD + quad * 8;
    const unsigned short* wp = Wt + (size_t)lr * KD + quad * 8;

    floatx4 acc[8];
#pragma unroll
    for (int nt = 0; nt < 8; nt++) acc[nt] = (floatx4){0.f, 0.f, 0.f, 0.f};

#pragma unroll 2
    for (int kt = 0; kt < 8; kt++) {
        union { short8 v; unsigned short us[8]; } av;
        if (ok) {
            const float4 f0 = *(const float4*)(xp + kt * 32);
            const float4 f1 = *(const float4*)(xp + kt * 32 + 4);
            av.us[0] = f2bf(f0.x); av.us[1] = f2bf(f0.y);
            av.us[2] = f2bf(f0.z); av.us[3] = f2bf(f0.w);
            av.us[4] = f2bf(f1.x); av.us[5] = f2bf(f1.y);
            av.us[6] = f2bf(f1.z); av.us[7] = f2bf(f1.w);
        } else {
            av.v = (short8){0,0,0,0,0,0,0,0};
        }
        short8 b[8];
#pragma unroll
        for (int nt = 0; nt < 8; nt++)
            b[nt] = *(const short8*)(wp + (size_t)nt * 16 * KD + kt * 32);
#pragma unroll
        for (int nt = 0; nt < 8; nt++)
            acc[nt] = __builtin_amdgcn_mfma_f32_16x16x32_bf16(av.v, b[nt], acc[nt], 0, 0, 0);
    }

#pragma unroll
    for (int i = 0; i < 4; i++) {
        const int grow = row0 + m0 + quad * 4 + i;
        if (grow < NN) {
            unsigned short* hp = hb + (size_t)grow * CD + lr;
#pragma unroll
            for (int nt = 0; nt < 8; nt++)
                hp[nt * 16] = f2bf(acc[nt][i]);
        }
    }
}

// ===== single-launch scan, WAVE-PARALLEL decoupled lookback =====
// state[b*8] u64 = {status:32 | value:32}; 0=invalid, 1=aggregate, 2=prefix.
// Flag+value travel in one relaxed agent-scope word (cross-XCD-safe pattern).
__global__ __launch_bounds__(256) void scan_lookback(
        const unsigned* __restrict__ packedAll,
        unsigned long long* __restrict__ state,
        int* __restrict__ start, int4* __restrict__ base4,
        float* __restrict__ dinv) {
    __shared__ int sm[256];
    __shared__ int sbase;
    const int t = threadIdx.x;
    const int b = blockIdx.x;
    const int g = b * 256 + t;

    int cc[4] = {0, 0, 0, 0};
    unsigned lowsum = 0;
    int v = 0;
    if (g < NN) {
#pragma unroll
        for (int c = 0; c < 4; c++) {
            unsigned p = packedAll[(size_t)c * NN + g];
            cc[c] = (int)(p >> 24);
            lowsum += p & 0xFFFFFFu;
            v += cc[c];
        }
    }
    sm[t] = v;
    __syncthreads();
#pragma unroll
    for (int off = 1; off < 256; off <<= 1) {
        int u = (t >= off) ? sm[t - off] : 0;
        __syncthreads();
        sm[t] += u;
        __syncthreads();
    }
    const int incl = sm[t];          // inclusive prefix within block
    const int total = sm[255];

    if (t == 0) {                    // publish immediately (b0: full prefix)
        unsigned long long post =
            ((b == 0 ? 2ull : 1ull) << 32) | (unsigned)total;
        __hip_atomic_store(&state[(size_t)b * 8], post,
                           __ATOMIC_RELAXED, __HIP_MEMORY_SCOPE_AGENT);
        if (b == 0) sbase = 0;
    }
    if (b > 0 && t < 64) {
        long long run = 0;
        int i = b - 1;
        while (true) {
            const int idx = i - t;
            unsigned long long s = (idx >= 0)
                ? __hip_atomic_load(&state[(size_t)idx * 8],
                                    __ATOMIC_RELAXED, __HIP_MEMORY_SCOPE_AGENT)
                : (2ull << 32);                      // virtual prefix-0 at -1
            const unsigned st = (unsigned)(s >> 32);
            const unsigned long long b0m = __ballot(st == 0u);
            const unsigned long long b2m = __ballot(st == 2u);
            if (b2m) {
                const int L = __ffsll((long long)b2m) - 1;   // nearest prefix
                const unsigned long long below =
                    (L == 63) ? ~0ull : ((1ull << (L + 1)) - 1ull);
                if (b0m & below) { __builtin_amdgcn_s_sleep(1); continue; }
                unsigned val = (t <= L) ? (unsigned)s : 0u;
#pragma unroll
                for (int o = 32; o; o >>= 1) val += __shfl_xor(val, o);
                run += val;
                break;
            } else if (b0m) {
                const int L0 = __ffsll((long long)b0m) - 1;  // consume < L0
                unsigned val = (t < L0) ? (unsigned)s : 0u;
#pragma unroll
                for (int o = 32; o; o >>= 1) val += __shfl_xor(val, o);
                run += val;
                i -= L0;
                if (L0 == 0) __builtin_amdgcn_s_sleep(1);
            } else {                                         // all aggregates
                unsigned val = (unsigned)s;
#pragma unroll
                for (int o = 32; o; o >>= 1) val += __shfl_xor(val, o);
                run += val;
                i -= 64;
            }
        }
        if (t == 0) {
            __hip_atomic_store(&state[(size_t)b * 8],
                               (2ull << 32) | (unsigned)(run + total),
                               __ATOMIC_RELAXED, __HIP_MEMORY_SCOPE_AGENT);
            sbase = (int)run;
        }
    }
    __syncthreads();
    const int base = sbase;

    if (g < NN) {
        const int s = base + (incl - v);
        start[g] = s;
        base4[g] = make_int4(s, s + cc[0], s + cc[0] + cc[1], s + cc[0] + cc[1] + cc[2]);
        float degs = (float)lowsum * (1.0f / 262144.0f);
        dinv[g] = rsqrtf(1.0f + degs);
    }
    if (g == 0) start[NN] = NE;
}

// -------- atomic-free CSR placement, 4 edges/thread vectorized:
// meta[base4[col][copy]+rank] = {bf16 dinv[row]*ew | u16 row}
__global__ __launch_bounds__(256) void meta_write(const int* __restrict__ row,
                                                  const int* __restrict__ col,
                                                  const float* __restrict__ ew,
                                                  const unsigned short* __restrict__ rank,
                                                  const int4* __restrict__ base4,
                                                  const float* __restrict__ dinv,
                                                  unsigned* __restrict__ meta) {
    const int e0 = (blockIdx.x * 256 + threadIdx.x) * 4;
    if (e0 >= NE) return;
    const int4 c4 = *(const int4*)(col + e0);
    const int4 r4 = *(const int4*)(row + e0);
    const float4 w4 = *(const float4*)(ew + e0);
    const ushort4 k4 = *(const ushort4*)(rank + e0);
    const int cs[4] = {c4.x, c4.y, c4.z, c4.w};
    const int rs[4] = {r4.x, r4.y, r4.z, r4.w};
    const float wsv[4] = {w4.x, w4.y, w4.z, w4.w};
    const unsigned short ks[4] = {k4.x, k4.y, k4.z, k4.w};
#pragma unroll
    for (int j = 0; j < 4; j++) {
        const int e = e0 + j;
        const int copy = (e >> 8) & 3;          // wave-uniform (256-edge runs)
        const int4 b4 = base4[cs[j]];
        const int base = (copy == 0) ? b4.x : (copy == 1) ? b4.y
                       : (copy == 2) ? b4.z : b4.w;
        const unsigned short wbf = f2bf(dinv[rs[j]] * wsv[j]);
        meta[base + ks[j]] = ((unsigned)wbf << 16) | (unsigned)rs[j];
    }
}

// ---------- pull aggregation: one wave per node, bf16 h, 8-way ILP, fused
// epilogue. meta is streamed nontemporally (no reuse) to keep L2 for hb.
__global__ __launch_bounds__(256) void aggregate(const int* __restrict__ start,
                                                 const unsigned* __restrict__ meta,
                                                 const unsigned short* __restrict__ hb,
                                                 const float* __restrict__ dinv,
                                                 const float* __restrict__ bias,
                                                 const float* __restrict__ alpha,
                                                 float* __restrict__ out) {
    int n = blockIdx.x * 4 + (threadIdx.x >> 6);
    if (n >= NN) return;
    n = __builtin_amdgcn_readfirstlane(n);
    const int lane = threadIdx.x & 63;
    const int s = __builtin_amdgcn_readfirstlane(start[n]);
    const int e = __builtin_amdgcn_readfirstlane(start[n + 1]);

    float A0[8], A1[8];
#pragma unroll
    for (int j = 0; j < 8; j++) { A0[j] = 0.f; A1[j] = 0.f; }

    int i = s;
    for (; i + 8 <= e; i += 8) {
        unsigned m[8], u[8];
#pragma unroll
        for (int j = 0; j < 8; j++) m[j] = __builtin_nontemporal_load(meta + i + j);
#pragma unroll
        for (int j = 0; j < 8; j++)
            u[j] = *(const unsigned*)(hb + (size_t)(m[j] & 0xFFFFu) * CD + lane * 2);
#pragma unroll
        for (int j = 0; j < 8; j++) {
            float w = __uint_as_float(m[j] & 0xFFFF0000u);
            A0[j] = fmaf(w, bf2f_lo(u[j]), A0[j]);
            A1[j] = fmaf(w, bf2f_hi(u[j]), A1[j]);
        }
    }
    for (; i < e; i++) {
        unsigned m = __builtin_nontemporal_load(meta + i);
        unsigned u = *(const unsigned*)(hb + (size_t)(m & 0xFFFFu) * CD + lane * 2);
        float w = __uint_as_float(m & 0xFFFF0000u);
        A0[0] = fmaf(w, bf2f_lo(u), A0[0]);
        A1[0] = fmaf(w, bf2f_hi(u), A1[0]);
    }
#pragma unroll
    for (int j = 1; j < 8; j++) { A0[0] += A0[j]; A1[0] += A1[j]; }

    const float dc = dinv[n];
    unsigned us = *(const unsigned*)(hb + (size_t)n * CD + lane * 2);
    const int ch = lane * 2;
    float o0 = dc * A0[0] + dc * dc * bf2f_lo(us) + bias[ch];
    float o1 = dc * A1[0] + dc * dc * bf2f_hi(us) + bias[ch + 1];
    o0 = o0 >= 0.f ? o0 : alpha[ch] * o0;
    o1 = o1 >= 0.f ? o1 : alpha[ch + 1] * o1;
    floatx2 o; o.x = o0; o.y = o1;
    __builtin_nontemporal_store(o, (floatx2*)(out + (size_t)n * CD + ch));
}

extern "C" void kernel_launch(void* const* d_in, const int* in_sizes, int n_in,
                              void* d_out, int out_size, void* d_ws, size_t ws_size,
                              hipStream_t stream) {
    const float* x     = (const float*)d_in[0];
    const int*   eidx  = (const int*)d_in[1];   // [2, NE]
    const float* ew    = (const float*)d_in[2];
    const float* Wm    = (const float*)d_in[3];
    const float* bias  = (const float*)d_in[4];
    const float* alpha = (const float*)d_in[5];
    const int* row = eidx;
    const int* col = eidx + NE;

    float* out = (float*)d_out;

    // workspace layout (bytes), no overlaps:
    char* ws = (char*)d_ws;
    unsigned* packedAll = (unsigned*)(ws);                   // 4*NN u32   [0, 800000)
    int*   start    = (int*)(ws + 800000);                   // NN+1 int   [800000, 1000004)
    float* dinv     = (float*)(ws + 1000064);                // NN f32     [1000064, 1200064)
    unsigned short* rank = (unsigned short*)(ws + 1200064);  // NE u16     [1200064, 2800064)
    int4*  base4    = (int4*)(ws + 2800064);                 // NN int4    [2800064, 3600064)
    unsigned* meta  = (unsigned*)(ws + 3600064);             // NE u32     [3600064, 6800064)
    unsigned short* Wt = (unsigned short*)(ws + 6800064);    // 128*256 bf16 [6800064, 6865600)
    unsigned long long* state = (unsigned long long*)(ws + 6865600); // NB*8 u64 [6865600, 6878144)
    unsigned short* hb = (unsigned short*)(ws + 6878208);    // 50176*128 bf16 [6878208, 19723264)

    prep          <<<NB + 32, 256, 0, stream>>>(Wm, Wt, packedAll, state);
    fused_gemm_hist<<<GEMM_BLOCKS + HIST4_BLOCKS, 256, 0, stream>>>(
                        x, Wt, hb, col, ew, packedAll, rank);
    scan_lookback <<<NB, 256, 0, stream>>>(packedAll, state, start, base4, dinv);
    meta_write    <<<META_BLOCKS, 256, 0, stream>>>(row, col, ew, rank, base4, dinv, meta);
    aggregate     <<<(NN + 3) / 4, 256, 0, stream>>>(start, meta, hb, dinv, bias, alpha, out);
}

// Round 9
// 188.313 us; speedup vs baseline: 1.1149x; 1.1149x over previous
//
#include <hip/hip_runtime.h>

#define NN 50000
#define NE 800000
#define KD 256
#define CD 128
#define NB 196            // scan blocks: 196*256 = 50176 >= NN
#define GEMM_BLOCKS 782   // (NN+63)/64
#define HIST_BLOCKS 3125  // (NE+255)/256, 1 edge/thread
#define META_BLOCKS 782   // 4 edges/thread

typedef __attribute__((ext_vector_type(8))) short short8;
typedef __attribute__((ext_vector_type(4))) float floatx4;
typedef __attribute__((ext_vector_type(2))) float floatx2;

__device__ inline unsigned short f2bf(float f) {
    unsigned u = __float_as_uint(f);
    unsigned r = (u + 0x7FFFu + ((u >> 16) & 1u)) >> 16;   // RNE
    return (unsigned short)r;
}
__device__ inline float bf2f_lo(unsigned u) { return __uint_as_float(u << 16); }
__device__ inline float bf2f_hi(unsigned u) { return __uint_as_float(u & 0xFFFF0000u); }

// ===== prep: zero u32 histogram shadows + scan state (blocks < NB),
// W transpose (last 32 blocks) =====
__global__ __launch_bounds__(256) void prep(const float* __restrict__ W,
                                            unsigned short* __restrict__ Wt,
                                            unsigned* __restrict__ packedAll,
                                            unsigned long long* __restrict__ state) {
    __shared__ unsigned short t[32][33];
    if (blockIdx.x < NB) {
        const int g = blockIdx.x * 256 + threadIdx.x;
        if (g < NN) {
#pragma unroll
            for (int c = 0; c < 4; c++) packedAll[(size_t)c * NN + g] = 0u;
        }
        if (blockIdx.x == 0) {
            for (int i = threadIdx.x; i < NB * 8; i += 256) state[i] = 0ull;
        }
        return;
    }
    const int b2 = blockIdx.x - NB;          // [0,32): 8 k-tiles x 4 n-tiles
    const int bk = (b2 & 7) * 32;
    const int bn = (b2 >> 3) * 32;
    const int tx = threadIdx.x & 31;
    const int ty = threadIdx.x >> 5;
#pragma unroll
    for (int i = 0; i < 32; i += 8)
        t[ty + i][tx] = f2bf(W[(size_t)(bk + ty + i) * CD + bn + tx]);
    __syncthreads();
#pragma unroll
    for (int i = 0; i < 32; i += 8)
        Wt[(size_t)(bn + ty + i) * KD + bk + tx] = t[tx][ty + i];
}

// ===== fused: hybrid GEMM tiles (blocks < GEMM_BLOCKS) + hist (rest) =====
// GEMM: A-fragments preloaded direct from x in consume layout (x rows have
// no cross-block reuse -> staging them through LDS was pure overhead); B
// (Wt, reused by every wave -> MUST be load-combined through LDS, round-8's
// direct-B thrashed L1 16-way) staged in four 16KB quarters, 2 MFMA K-steps
// per stage. 7 barriers/block vs round-7's 16, conflict-free pad.
// hist: packed {count:8 | sum(ew) Q6.18:24}, 4 shadow copies (copy=hblk&3
// == (e>>8)&3, matches meta_write). Round-7's proven config.
__global__ __launch_bounds__(256) void fused_gemm_hist(
        const float* __restrict__ x, const unsigned short* __restrict__ Wt,
        unsigned short* __restrict__ hb,
        const int* __restrict__ col, const float* __restrict__ ew,
        unsigned* __restrict__ packedAll, unsigned short* __restrict__ rank) {
    __shared__ unsigned short Bs[128][68];   // 17408 B; pad 4: row stride 34 dw
                                             // -> b128 start banks uniform

    if (blockIdx.x >= GEMM_BLOCKS) {
        const int hblk = blockIdx.x - GEMM_BLOCKS;
        const int e = hblk * 256 + threadIdx.x;
        if (e < NE) {
            unsigned* packed = packedAll + (size_t)(hblk & 3) * NN;
            unsigned p = (1u << 24) + (unsigned)(ew[e] * 262144.0f);
            unsigned old = atomicAdd(&packed[col[e]], p);
            rank[e] = (unsigned short)(old >> 24);   // rank within copy
        }
        return;
    }

    // ---------------- GEMM role: h = bf16(x) @ Wt^T, 64 rows x 128 ch / block
    const int tid  = threadIdx.x;
    const int wave = tid >> 6;
    const int lane = tid & 63;
    const int row0 = blockIdx.x * 64;
    const int m0   = wave * 16;
    const int lr   = lane & 15;
    const int quad = lane >> 4;

    const int grow_a = row0 + m0 + lr;           // A row this lane consumes
    const bool ok = grow_a < NN;
    const float* xp = x + (size_t)grow_a * KD + quad * 8;

    // Preload ALL A fragments (8 x 32B independent loads, front-loaded; their
    // latency hides under the first B staging).
    union { short8 v; unsigned short us[8]; } avs[8];
#pragma unroll
    for (int kt = 0; kt < 8; kt++) {
        if (ok) {
            const float4 f0 = *(const float4*)(xp + kt * 32);
            const float4 f1 = *(const float4*)(xp + kt * 32 + 4);
            avs[kt].us[0] = f2bf(f0.x); avs[kt].us[1] = f2bf(f0.y);
            avs[kt].us[2] = f2bf(f0.z); avs[kt].us[3] = f2bf(f0.w);
            avs[kt].us[4] = f2bf(f1.x); avs[kt].us[5] = f2bf(f1.y);
            avs[kt].us[6] = f2bf(f1.z); avs[kt].us[7] = f2bf(f1.w);
        } else {
            avs[kt].v = (short8){0,0,0,0,0,0,0,0};
        }
    }

    floatx4 acc[8];
#pragma unroll
    for (int nt = 0; nt < 8; nt++) acc[nt] = (floatx4){0.f, 0.f, 0.f, 0.f};

#pragma unroll
    for (int kq = 0; kq < 4; kq++) {             // four 64-k quarters
        if (kq) __syncthreads();                 // protect Bs overwrite
        // stage quarter: 128 rows x 64 k x 2B = 16KB; 4 rounds x 256thr x 16B
#pragma unroll
        for (int r8 = 0; r8 < 4; r8++) {
            const int idx  = r8 * 256 + tid;     // 1024 chunks of 8 bf16
            const int rown = idx >> 3;           // 8 chunks per 64-k row
            const int koff = (idx & 7) * 8;
            *(short8*)&Bs[rown][koff] =
                *(const short8*)(Wt + (size_t)rown * KD + kq * 64 + koff);
        }
        __syncthreads();
#pragma unroll
        for (int kt2 = 0; kt2 < 2; kt2++) {
            const int kt = kq * 2 + kt2;
            short8 b[8];
#pragma unroll
            for (int nt = 0; nt < 8; nt++)
                b[nt] = *(const short8*)&Bs[nt * 16 + lr][kt2 * 32 + quad * 8];
#pragma unroll
            for (int nt = 0; nt < 8; nt++)
                acc[nt] = __builtin_amdgcn_mfma_f32_16x16x32_bf16(
                              avs[kt].v, b[nt], acc[nt], 0, 0, 0);
        }
    }

#pragma unroll
    for (int i = 0; i < 4; i++) {
        const int grow = row0 + m0 + quad * 4 + i;
        if (grow < NN) {
            unsigned short* hp = hb + (size_t)grow * CD + lr;
#pragma unroll
            for (int nt = 0; nt < 8; nt++)
                hp[nt * 16] = f2bf(acc[nt][i]);
        }
    }
}

// ===== single-launch scan, WAVE-PARALLEL decoupled lookback =====
// state[b*8] u64 = {status:32 | value:32}; 0=invalid, 1=aggregate, 2=prefix.
// Flag+value travel in one relaxed agent-scope word (cross-XCD-safe pattern).
__global__ __launch_bounds__(256) void scan_lookback(
        const unsigned* __restrict__ packedAll,
        unsigned long long* __restrict__ state,
        int* __restrict__ start, int4* __restrict__ base4,
        float* __restrict__ dinv) {
    __shared__ int sm[256];
    __shared__ int sbase;
    const int t = threadIdx.x;
    const int b = blockIdx.x;
    const int g = b * 256 + t;

    int cc[4] = {0, 0, 0, 0};
    unsigned lowsum = 0;
    int v = 0;
    if (g < NN) {
#pragma unroll
        for (int c = 0; c < 4; c++) {
            unsigned p = packedAll[(size_t)c * NN + g];
            cc[c] = (int)(p >> 24);
            lowsum += p & 0xFFFFFFu;
            v += cc[c];
        }
    }
    sm[t] = v;
    __syncthreads();
#pragma unroll
    for (int off = 1; off < 256; off <<= 1) {
        int u = (t >= off) ? sm[t - off] : 0;
        __syncthreads();
        sm[t] += u;
        __syncthreads();
    }
    const int incl = sm[t];          // inclusive prefix within block
    const int total = sm[255];

    if (t == 0) {                    // publish immediately (b0: full prefix)
        unsigned long long post =
            ((b == 0 ? 2ull : 1ull) << 32) | (unsigned)total;
        __hip_atomic_store(&state[(size_t)b * 8], post,
                           __ATOMIC_RELAXED, __HIP_MEMORY_SCOPE_AGENT);
        if (b == 0) sbase = 0;
    }
    if (b > 0 && t < 64) {
        long long run = 0;
        int i = b - 1;
        while (true) {
            const int idx = i - t;
            unsigned long long s = (idx >= 0)
                ? __hip_atomic_load(&state[(size_t)idx * 8],
                                    __ATOMIC_RELAXED, __HIP_MEMORY_SCOPE_AGENT)
                : (2ull << 32);                      // virtual prefix-0 at -1
            const unsigned st = (unsigned)(s >> 32);
            const unsigned long long b0m = __ballot(st == 0u);
            const unsigned long long b2m = __ballot(st == 2u);
            if (b2m) {
                const int L = __ffsll((long long)b2m) - 1;   // nearest prefix
                const unsigned long long below =
                    (L == 63) ? ~0ull : ((1ull << (L + 1)) - 1ull);
                if (b0m & below) { __builtin_amdgcn_s_sleep(1); continue; }
                unsigned val = (t <= L) ? (unsigned)s : 0u;
#pragma unroll
                for (int o = 32; o; o >>= 1) val += __shfl_xor(val, o);
                run += val;
                break;
            } else if (b0m) {
                const int L0 = __ffsll((long long)b0m) - 1;  // consume < L0
                unsigned val = (t < L0) ? (unsigned)s : 0u;
#pragma unroll
                for (int o = 32; o; o >>= 1) val += __shfl_xor(val, o);
                run += val;
                i -= L0;
                if (L0 == 0) __builtin_amdgcn_s_sleep(1);
            } else {                                         // all aggregates
                unsigned val = (unsigned)s;
#pragma unroll
                for (int o = 32; o; o >>= 1) val += __shfl_xor(val, o);
                run += val;
                i -= 64;
            }
        }
        if (t == 0) {
            __hip_atomic_store(&state[(size_t)b * 8],
                               (2ull << 32) | (unsigned)(run + total),
                               __ATOMIC_RELAXED, __HIP_MEMORY_SCOPE_AGENT);
            sbase = (int)run;
        }
    }
    __syncthreads();
    const int base = sbase;

    if (g < NN) {
        const int s = base + (incl - v);
        start[g] = s;
        base4[g] = make_int4(s, s + cc[0], s + cc[0] + cc[1], s + cc[0] + cc[1] + cc[2]);
        float degs = (float)lowsum * (1.0f / 262144.0f);
        dinv[g] = rsqrtf(1.0f + degs);
    }
    if (g == 0) start[NN] = NE;
}

// -------- atomic-free CSR placement, 4 edges/thread vectorized:
// meta[base4[col][copy]+rank] = {bf16 dinv[row]*ew | u16 row}
__global__ __launch_bounds__(256) void meta_write(const int* __restrict__ row,
                                                  const int* __restrict__ col,
                                                  const float* __restrict__ ew,
                                                  const unsigned short* __restrict__ rank,
                                                  const int4* __restrict__ base4,
                                                  const float* __restrict__ dinv,
                                                  unsigned* __restrict__ meta) {
    const int e0 = (blockIdx.x * 256 + threadIdx.x) * 4;
    if (e0 >= NE) return;
    const int4 c4 = *(const int4*)(col + e0);
    const int4 r4 = *(const int4*)(row + e0);
    const float4 w4 = *(const float4*)(ew + e0);
    const ushort4 k4 = *(const ushort4*)(rank + e0);
    const int cs[4] = {c4.x, c4.y, c4.z, c4.w};
    const int rs[4] = {r4.x, r4.y, r4.z, r4.w};
    const float wsv[4] = {w4.x, w4.y, w4.z, w4.w};
    const unsigned short ks[4] = {k4.x, k4.y, k4.z, k4.w};
#pragma unroll
    for (int j = 0; j < 4; j++) {
        const int e = e0 + j;
        const int copy = (e >> 8) & 3;          // wave-uniform (256-edge runs)
        const int4 b4 = base4[cs[j]];
        const int base = (copy == 0) ? b4.x : (copy == 1) ? b4.y
                       : (copy == 2) ? b4.z : b4.w;
        const unsigned short wbf = f2bf(dinv[rs[j]] * wsv[j]);
        meta[base + ks[j]] = ((unsigned)wbf << 16) | (unsigned)rs[j];
    }
}

// ---------- pull aggregation: one wave per node, bf16 h, 8-way ILP, fused
// epilogue. meta is streamed nontemporally (no reuse) to keep L2 for hb.
__global__ __launch_bounds__(256) void aggregate(const int* __restrict__ start,
                                                 const unsigned* __restrict__ meta,
                                                 const unsigned short* __restrict__ hb,
                                                 const float* __restrict__ dinv,
                                                 const float* __restrict__ bias,
                                                 const float* __restrict__ alpha,
                                                 float* __restrict__ out) {
    int n = blockIdx.x * 4 + (threadIdx.x >> 6);
    if (n >= NN) return;
    n = __builtin_amdgcn_readfirstlane(n);
    const int lane = threadIdx.x & 63;
    const int s = __builtin_amdgcn_readfirstlane(start[n]);
    const int e = __builtin_amdgcn_readfirstlane(start[n + 1]);

    float A0[8], A1[8];
#pragma unroll
    for (int j = 0; j < 8; j++) { A0[j] = 0.f; A1[j] = 0.f; }

    int i = s;
    for (; i + 8 <= e; i += 8) {
        unsigned m[8], u[8];
#pragma unroll
        for (int j = 0; j < 8; j++) m[j] = __builtin_nontemporal_load(meta + i + j);
#pragma unroll
        for (int j = 0; j < 8; j++)
            u[j] = *(const unsigned*)(hb + (size_t)(m[j] & 0xFFFFu) * CD + lane * 2);
#pragma unroll
        for (int j = 0; j < 8; j++) {
            float w = __uint_as_float(m[j] & 0xFFFF0000u);
            A0[j] = fmaf(w, bf2f_lo(u[j]), A0[j]);
            A1[j] = fmaf(w, bf2f_hi(u[j]), A1[j]);
        }
    }
    for (; i < e; i++) {
        unsigned m = __builtin_nontemporal_load(meta + i);
        unsigned u = *(const unsigned*)(hb + (size_t)(m & 0xFFFFu) * CD + lane * 2);
        float w = __uint_as_float(m & 0xFFFF0000u);
        A0[0] = fmaf(w, bf2f_lo(u), A0[0]);
        A1[0] = fmaf(w, bf2f_hi(u), A1[0]);
    }
#pragma unroll
    for (int j = 1; j < 8; j++) { A0[0] += A0[j]; A1[0] += A1[j]; }

    const float dc = dinv[n];
    unsigned us = *(const unsigned*)(hb + (size_t)n * CD + lane * 2);
    const int ch = lane * 2;
    float o0 = dc * A0[0] + dc * dc * bf2f_lo(us) + bias[ch];
    float o1 = dc * A1[0] + dc * dc * bf2f_hi(us) + bias[ch + 1];
    o0 = o0 >= 0.f ? o0 : alpha[ch] * o0;
    o1 = o1 >= 0.f ? o1 : alpha[ch + 1] * o1;
    floatx2 o; o.x = o0; o.y = o1;
    __builtin_nontemporal_store(o, (floatx2*)(out + (size_t)n * CD + ch));
}

extern "C" void kernel_launch(void* const* d_in, const int* in_sizes, int n_in,
                              void* d_out, int out_size, void* d_ws, size_t ws_size,
                              hipStream_t stream) {
    const float* x     = (const float*)d_in[0];
    const int*   eidx  = (const int*)d_in[1];   // [2, NE]
    const float* ew    = (const float*)d_in[2];
    const float* Wm    = (const float*)d_in[3];
    const float* bias  = (const float*)d_in[4];
    const float* alpha = (const float*)d_in[5];
    const int* row = eidx;
    const int* col = eidx + NE;

    float* out = (float*)d_out;

    // workspace layout (bytes), no overlaps:
    char* ws = (char*)d_ws;
    unsigned* packedAll = (unsigned*)(ws);                   // 4*NN u32   [0, 800000)
    int*   start    = (int*)(ws + 800000);                   // NN+1 int   [800000, 1000004)
    float* dinv     = (float*)(ws + 1000064);                // NN f32     [1000064, 1200064)
    unsigned short* rank = (unsigned short*)(ws + 1200064);  // NE u16     [1200064, 2800064)
    int4*  base4    = (int4*)(ws + 2800064);                 // NN int4    [2800064, 3600064)
    unsigned* meta  = (unsigned*)(ws + 3600064);             // NE u32     [3600064, 6800064)
    unsigned short* Wt = (unsigned short*)(ws + 6800064);    // 128*256 bf16 [6800064, 6865600)
    unsigned long long* state = (unsigned long long*)(ws + 6865600); // NB*8 u64 [6865600, 6878144)
    unsigned short* hb = (unsigned short*)(ws + 6878208);    // 50176*128 bf16 [6878208, 19723264)

    prep          <<<NB + 32, 256, 0, stream>>>(Wm, Wt, packedAll, state);
    fused_gemm_hist<<<GEMM_BLOCKS + HIST_BLOCKS, 256, 0, stream>>>(
                        x, Wt, hb, col, ew, packedAll, rank);
    scan_lookback <<<NB, 256, 0, stream>>>(packedAll, state, start, base4, dinv);
    meta_write    <<<META_BLOCKS, 256, 0, stream>>>(row, col, ew, rank, base4, dinv, meta);
    aggregate     <<<(NN + 3) / 4, 256, 0, stream>>>(start, meta, hb, dinv, bias, alpha, out);
}

// Round 10
// 187.707 us; speedup vs baseline: 1.1185x; 1.0032x over previous
//
#include <hip/hip_runtime.h>

#define NN 50000
#define NE 800000
#define KD 256
#define CD 128
#define NB 196            // scan blocks: 196*256 = 50176 >= NN
#define GEMM_BLOCKS 782   // (NN+63)/64
#define HIST_BLOCKS 3125  // (NE+255)/256, 1 edge/thread
#define META_BLOCKS 782   // 4 edges/thread
#define NCOPY 8           // one histogram shadow per XCD

typedef __attribute__((ext_vector_type(8))) short short8;
typedef __attribute__((ext_vector_type(4))) float floatx4;
typedef __attribute__((ext_vector_type(2))) float floatx2;

__device__ inline unsigned short f2bf(float f) {
    unsigned u = __float_as_uint(f);
    unsigned r = (u + 0x7FFFu + ((u >> 16) & 1u)) >> 16;   // RNE
    return (unsigned short)r;
}
__device__ inline float bf2f_lo(unsigned u) { return __uint_as_float(u << 16); }
__device__ inline float bf2f_hi(unsigned u) { return __uint_as_float(u & 0xFFFF0000u); }

// Physical XCD id of this block's CU (0..7). HW-verified on MI355X
// (learn_hip m09). Uniform across the block (block -> one CU -> one XCD).
__device__ inline unsigned xcd_id() {
    unsigned x;
    asm volatile("s_getreg_b32 %0, hwreg(HW_REG_XCC_ID)" : "=s"(x));
    return x & (NCOPY - 1);
}

// ===== prep: zero u32 histogram shadows + scan state (blocks < NB),
// W transpose (last 32 blocks) =====
__global__ __launch_bounds__(256) void prep(const float* __restrict__ W,
                                            unsigned short* __restrict__ Wt,
                                            unsigned* __restrict__ packedAll,
                                            unsigned long long* __restrict__ state) {
    __shared__ unsigned short t[32][33];
    if (blockIdx.x < NB) {
        const int g = blockIdx.x * 256 + threadIdx.x;
        if (g < NN) {
#pragma unroll
            for (int c = 0; c < NCOPY; c++) packedAll[(size_t)c * NN + g] = 0u;
        }
        if (blockIdx.x == 0) {
            for (int i = threadIdx.x; i < NB * 8; i += 256) state[i] = 0ull;
        }
        return;
    }
    const int b2 = blockIdx.x - NB;          // [0,32): 8 k-tiles x 4 n-tiles
    const int bk = (b2 & 7) * 32;
    const int bn = (b2 >> 3) * 32;
    const int tx = threadIdx.x & 31;
    const int ty = threadIdx.x >> 5;
#pragma unroll
    for (int i = 0; i < 32; i += 8)
        t[ty + i][tx] = f2bf(W[(size_t)(bk + ty + i) * CD + bn + tx]);
    __syncthreads();
#pragma unroll
    for (int i = 0; i < 32; i += 8)
        Wt[(size_t)(bn + ty + i) * KD + bk + tx] = t[tx][ty + i];
}

// ===== fused: hybrid GEMM tiles (blocks < GEMM_BLOCKS) + XCD-local hist =====
// hist: device-scope atomics (~19 G/s at the cross-XCD coherence point) were
// the kernel's 43us floor — invariant to GEMM structure (r7/r8/r9 evidence).
// Now: one shadow copy per XCD; all writers of copy c share XCD c's L2, so
// WORKGROUP-scope atomics (executed in-L2, no sc1 bypass) are correct and
// fast. rank[e] = {copy:3 | cnt:8} since copy is scheduling-dependent.
// Packed field {count:8 | sum(ew) Q6.18:24}; per-(node,copy) count <= ~45.
// GEMM: A direct-from-x in consume layout; B (reused) staged via LDS in
// four 16KB quarters, conflict-free pad (r9, bank conflicts = 0).
__global__ __launch_bounds__(256) void fused_gemm_hist(
        const float* __restrict__ x, const unsigned short* __restrict__ Wt,
        unsigned short* __restrict__ hb,
        const int* __restrict__ col, const float* __restrict__ ew,
        unsigned* __restrict__ packedAll, unsigned short* __restrict__ rank) {
    __shared__ unsigned short Bs[128][68];   // 17408 B; row stride 34 dwords

    if (blockIdx.x >= GEMM_BLOCKS) {
        const int hblk = blockIdx.x - GEMM_BLOCKS;
        const int e = hblk * 256 + threadIdx.x;
        if (e < NE) {
            const unsigned copy = xcd_id();
            unsigned* packed = packedAll + (size_t)copy * NN;
            unsigned p = (1u << 24) + (unsigned)(ew[e] * 262144.0f);
            unsigned old = __hip_atomic_fetch_add(&packed[col[e]], p,
                               __ATOMIC_RELAXED, __HIP_MEMORY_SCOPE_WORKGROUP);
            rank[e] = (unsigned short)((copy << 8) | (old >> 24));
        }
        return;
    }

    // ---------------- GEMM role: h = bf16(x) @ Wt^T, 64 rows x 128 ch / block
    const int tid  = threadIdx.x;
    const int wave = tid >> 6;
    const int lane = tid & 63;
    const int row0 = blockIdx.x * 64;
    const int m0   = wave * 16;
    const int lr   = lane & 15;
    const int quad = lane >> 4;

    const int grow_a = row0 + m0 + lr;           // A row this lane consumes
    const bool ok = grow_a < NN;
    const float* xp = x + (size_t)grow_a * KD + quad * 8;

    // Preload ALL A fragments (8 x 32B independent loads, front-loaded; their
    // latency hides under the first B staging).
    union { short8 v; unsigned short us[8]; } avs[8];
#pragma unroll
    for (int kt = 0; kt < 8; kt++) {
        if (ok) {
            const float4 f0 = *(const float4*)(xp + kt * 32);
            const float4 f1 = *(const float4*)(xp + kt * 32 + 4);
            avs[kt].us[0] = f2bf(f0.x); avs[kt].us[1] = f2bf(f0.y);
            avs[kt].us[2] = f2bf(f0.z); avs[kt].us[3] = f2bf(f0.w);
            avs[kt].us[4] = f2bf(f1.x); avs[kt].us[5] = f2bf(f1.y);
            avs[kt].us[6] = f2bf(f1.z); avs[kt].us[7] = f2bf(f1.w);
        } else {
            avs[kt].v = (short8){0,0,0,0,0,0,0,0};
        }
    }

    floatx4 acc[8];
#pragma unroll
    for (int nt = 0; nt < 8; nt++) acc[nt] = (floatx4){0.f, 0.f, 0.f, 0.f};

#pragma unroll
    for (int kq = 0; kq < 4; kq++) {             // four 64-k quarters
        if (kq) __syncthreads();                 // protect Bs overwrite
        // stage quarter: 128 rows x 64 k x 2B = 16KB; 4 rounds x 256thr x 16B
#pragma unroll
        for (int r8 = 0; r8 < 4; r8++) {
            const int idx  = r8 * 256 + tid;     // 1024 chunks of 8 bf16
            const int rown = idx >> 3;           // 8 chunks per 64-k row
            const int koff = (idx & 7) * 8;
            *(short8*)&Bs[rown][koff] =
                *(const short8*)(Wt + (size_t)rown * KD + kq * 64 + koff);
        }
        __syncthreads();
#pragma unroll
        for (int kt2 = 0; kt2 < 2; kt2++) {
            const int kt = kq * 2 + kt2;
            short8 b[8];
#pragma unroll
            for (int nt = 0; nt < 8; nt++)
                b[nt] = *(const short8*)&Bs[nt * 16 + lr][kt2 * 32 + quad * 8];
#pragma unroll
            for (int nt = 0; nt < 8; nt++)
                acc[nt] = __builtin_amdgcn_mfma_f32_16x16x32_bf16(
                              avs[kt].v, b[nt], acc[nt], 0, 0, 0);
        }
    }

#pragma unroll
    for (int i = 0; i < 4; i++) {
        const int grow = row0 + m0 + quad * 4 + i;
        if (grow < NN) {
            unsigned short* hp = hb + (size_t)grow * CD + lr;
#pragma unroll
            for (int nt = 0; nt < 8; nt++)
                hp[nt * 16] = f2bf(acc[nt][i]);
        }
    }
}

// ===== single-launch scan, WAVE-PARALLEL decoupled lookback =====
// state[b*8] u64 = {status:32 | value:32}; 0=invalid, 1=aggregate, 2=prefix.
// Flag+value travel in one relaxed agent-scope word (cross-XCD-safe pattern).
// Emits per-copy bases base8[n*8+j] (copy is XCD-indexed now).
__global__ __launch_bounds__(256) void scan_lookback(
        const unsigned* __restrict__ packedAll,
        unsigned long long* __restrict__ state,
        int* __restrict__ start, int* __restrict__ base8,
        float* __restrict__ dinv) {
    __shared__ int sm[256];
    __shared__ int sbase;
    const int t = threadIdx.x;
    const int b = blockIdx.x;
    const int g = b * 256 + t;

    int cc[NCOPY];
    unsigned lowsum = 0;
    int v = 0;
#pragma unroll
    for (int c = 0; c < NCOPY; c++) cc[c] = 0;
    if (g < NN) {
#pragma unroll
        for (int c = 0; c < NCOPY; c++) {
            unsigned p = packedAll[(size_t)c * NN + g];
            cc[c] = (int)(p >> 24);
            lowsum += p & 0xFFFFFFu;
            v += cc[c];
        }
    }
    sm[t] = v;
    __syncthreads();
#pragma unroll
    for (int off = 1; off < 256; off <<= 1) {
        int u = (t >= off) ? sm[t - off] : 0;
        __syncthreads();
        sm[t] += u;
        __syncthreads();
    }
    const int incl = sm[t];          // inclusive prefix within block
    const int total = sm[255];

    if (t == 0) {                    // publish immediately (b0: full prefix)
        unsigned long long post =
            ((b == 0 ? 2ull : 1ull) << 32) | (unsigned)total;
        __hip_atomic_store(&state[(size_t)b * 8], post,
                           __ATOMIC_RELAXED, __HIP_MEMORY_SCOPE_AGENT);
        if (b == 0) sbase = 0;
    }
    if (b > 0 && t < 64) {
        long long run = 0;
        int i = b - 1;
        while (true) {
            const int idx = i - t;
            unsigned long long s = (idx >= 0)
                ? __hip_atomic_load(&state[(size_t)idx * 8],
                                    __ATOMIC_RELAXED, __HIP_MEMORY_SCOPE_AGENT)
                : (2ull << 32);                      // virtual prefix-0 at -1
            const unsigned st = (unsigned)(s >> 32);
            const unsigned long long b0m = __ballot(st == 0u);
            const unsigned long long b2m = __ballot(st == 2u);
            if (b2m) {
                const int L = __ffsll((long long)b2m) - 1;   // nearest prefix
                const unsigned long long below =
                    (L == 63) ? ~0ull : ((1ull << (L + 1)) - 1ull);
                if (b0m & below) { __builtin_amdgcn_s_sleep(1); continue; }
                unsigned val = (t <= L) ? (unsigned)s : 0u;
#pragma unroll
                for (int o = 32; o; o >>= 1) val += __shfl_xor(val, o);
                run += val;
                break;
            } else if (b0m) {
                const int L0 = __ffsll((long long)b0m) - 1;  // consume < L0
                unsigned val = (t < L0) ? (unsigned)s : 0u;
#pragma unroll
                for (int o = 32; o; o >>= 1) val += __shfl_xor(val, o);
                run += val;
                i -= L0;
                if (L0 == 0) __builtin_amdgcn_s_sleep(1);
            } else {                                         // all aggregates
                unsigned val = (unsigned)s;
#pragma unroll
                for (int o = 32; o; o >>= 1) val += __shfl_xor(val, o);
                run += val;
                i -= 64;
            }
        }
        if (t == 0) {
            __hip_atomic_store(&state[(size_t)b * 8],
                               (2ull << 32) | (unsigned)(run + total),
                               __ATOMIC_RELAXED, __HIP_MEMORY_SCOPE_AGENT);
            sbase = (int)run;
        }
    }
    __syncthreads();
    const int base = sbase;

    if (g < NN) {
        const int s = base + (incl - v);
        start[g] = s;
        int pfx = s;
#pragma unroll
        for (int j = 0; j < NCOPY; j++) {        // 32B contiguous per thread
            base8[(size_t)g * NCOPY + j] = pfx;
            pfx += cc[j];
        }
        float degs = (float)lowsum * (1.0f / 262144.0f);
        dinv[g] = rsqrtf(1.0f + degs);
    }
    if (g == 0) start[NN] = NE;
}

// -------- atomic-free CSR placement, 4 edges/thread vectorized:
// meta[base8[col][copy]+cnt] = {bf16 dinv[row]*ew | u16 row};
// copy/cnt unpacked from rank[e] = {copy:3 | cnt:8}.
__global__ __launch_bounds__(256) void meta_write(const int* __restrict__ row,
                                                  const int* __restrict__ col,
                                                  const float* __restrict__ ew,
                                                  const unsigned short* __restrict__ rank,
                                                  const int* __restrict__ base8,
                                                  const float* __restrict__ dinv,
                                                  unsigned* __restrict__ meta) {
    const int e0 = (blockIdx.x * 256 + threadIdx.x) * 4;
    if (e0 >= NE) return;
    const int4 c4 = *(const int4*)(col + e0);
    const int4 r4 = *(const int4*)(row + e0);
    const float4 w4 = *(const float4*)(ew + e0);
    const ushort4 k4 = *(const ushort4*)(rank + e0);
    const int cs[4] = {c4.x, c4.y, c4.z, c4.w};
    const int rs[4] = {r4.x, r4.y, r4.z, r4.w};
    const float wsv[4] = {w4.x, w4.y, w4.z, w4.w};
    const unsigned short ks[4] = {k4.x, k4.y, k4.z, k4.w};
#pragma unroll
    for (int j = 0; j < 4; j++) {
        const int copy = ks[j] >> 8;
        const int cnt  = ks[j] & 255;
        const int base = base8[(size_t)cs[j] * NCOPY + copy];
        const unsigned short wbf = f2bf(dinv[rs[j]] * wsv[j]);
        meta[base + cnt] = ((unsigned)wbf << 16) | (unsigned)rs[j];
    }
}

// ---------- pull aggregation: one wave per node, bf16 h, 8-way ILP, fused
// epilogue. meta is streamed nontemporally (no reuse) to keep L2 for hb.
__global__ __launch_bounds__(256) void aggregate(const int* __restrict__ start,
                                                 const unsigned* __restrict__ meta,
                                                 const unsigned short* __restrict__ hb,
                                                 const float* __restrict__ dinv,
                                                 const float* __restrict__ bias,
                                                 const float* __restrict__ alpha,
                                                 float* __restrict__ out) {
    int n = blockIdx.x * 4 + (threadIdx.x >> 6);
    if (n >= NN) return;
    n = __builtin_amdgcn_readfirstlane(n);
    const int lane = threadIdx.x & 63;
    const int s = __builtin_amdgcn_readfirstlane(start[n]);
    const int e = __builtin_amdgcn_readfirstlane(start[n + 1]);

    float A0[8], A1[8];
#pragma unroll
    for (int j = 0; j < 8; j++) { A0[j] = 0.f; A1[j] = 0.f; }

    int i = s;
    for (; i + 8 <= e; i += 8) {
        unsigned m[8], u[8];
#pragma unroll
        for (int j = 0; j < 8; j++) m[j] = __builtin_nontemporal_load(meta + i + j);
#pragma unroll
        for (int j = 0; j < 8; j++)
            u[j] = *(const unsigned*)(hb + (size_t)(m[j] & 0xFFFFu) * CD + lane * 2);
#pragma unroll
        for (int j = 0; j < 8; j++) {
            float w = __uint_as_float(m[j] & 0xFFFF0000u);
            A0[j] = fmaf(w, bf2f_lo(u[j]), A0[j]);
            A1[j] = fmaf(w, bf2f_hi(u[j]), A1[j]);
        }
    }
    for (; i < e; i++) {
        unsigned m = __builtin_nontemporal_load(meta + i);
        unsigned u = *(const unsigned*)(hb + (size_t)(m & 0xFFFFu) * CD + lane * 2);
        float w = __uint_as_float(m & 0xFFFF0000u);
        A0[0] = fmaf(w, bf2f_lo(u), A0[0]);
        A1[0] = fmaf(w, bf2f_hi(u), A1[0]);
    }
#pragma unroll
    for (int j = 1; j < 8; j++) { A0[0] += A0[j]; A1[0] += A1[j]; }

    const float dc = dinv[n];
    unsigned us = *(const unsigned*)(hb + (size_t)n * CD + lane * 2);
    const int ch = lane * 2;
    float o0 = dc * A0[0] + dc * dc * bf2f_lo(us) + bias[ch];
    float o1 = dc * A1[0] + dc * dc * bf2f_hi(us) + bias[ch + 1];
    o0 = o0 >= 0.f ? o0 : alpha[ch] * o0;
    o1 = o1 >= 0.f ? o1 : alpha[ch + 1] * o1;
    floatx2 o; o.x = o0; o.y = o1;
    __builtin_nontemporal_store(o, (floatx2*)(out + (size_t)n * CD + ch));
}

extern "C" void kernel_launch(void* const* d_in, const int* in_sizes, int n_in,
                              void* d_out, int out_size, void* d_ws, size_t ws_size,
                              hipStream_t stream) {
    const float* x     = (const float*)d_in[0];
    const int*   eidx  = (const int*)d_in[1];   // [2, NE]
    const float* ew    = (const float*)d_in[2];
    const float* Wm    = (const float*)d_in[3];
    const float* bias  = (const float*)d_in[4];
    const float* alpha = (const float*)d_in[5];
    const int* row = eidx;
    const int* col = eidx + NE;

    float* out = (float*)d_out;

    // workspace layout (bytes), no overlaps:
    char* ws = (char*)d_ws;
    unsigned* packedAll = (unsigned*)(ws);                   // 8*NN u32   [0, 1600000)
    int*   start    = (int*)(ws + 1600000);                  // NN+1 int   [1600000, 1800004)
    float* dinv     = (float*)(ws + 1800064);                // NN f32     [1800064, 2000064)
    unsigned short* rank = (unsigned short*)(ws + 2000064);  // NE u16     [2000064, 3600064)
    int*   base8    = (int*)(ws + 3600064);                  // NN*8 int   [3600064, 5200064)
    unsigned* meta  = (unsigned*)(ws + 5200064);             // NE u32     [5200064, 8400064)
    unsigned short* Wt = (unsigned short*)(ws + 8400064);    // 128*256 bf16 [8400064, 8465600)
    unsigned long long* state = (unsigned long long*)(ws + 8465600); // NB*8 u64 [8465600, 8478144)
    unsigned short* hb = (unsigned short*)(ws + 8478208);    // 50176*128 bf16 [8478208, 21323264)

    prep          <<<NB + 32, 256, 0, stream>>>(Wm, Wt, packedAll, state);
    fused_gemm_hist<<<GEMM_BLOCKS + HIST_BLOCKS, 256, 0, stream>>>(
                        x, Wt, hb, col, ew, packedAll, rank);
    scan_lookback <<<NB, 256, 0, stream>>>(packedAll, state, start, base8, dinv);
    meta_write    <<<META_BLOCKS, 256, 0, stream>>>(row, col, ew, rank, base8, dinv, meta);
    aggregate     <<<(NN + 3) / 4, 256, 0, stream>>>(start, meta, hb, dinv, bias, alpha, out);
}